// Round 20
// baseline (15184.920 us; speedup 1.0000x reference)
//
#include <hip/hip_runtime.h>
#include <hip/hip_bf16.h>
#include <math.h>

#define B_   64
#define T_   256
#define DIN_ 512
#define H_   512
#define D_   1024
#define O_   1536
#define TB_  (T_*B_)
#define EPSf 1e-5f
#define NWG  96          // col-WGs per domain
#define NDOM 4           // batch domains of 16 rows
#define NSLOT (T_ + 6)   // wavefront slots: t = s - 2l

typedef short  bf16x8 __attribute__((ext_vector_type(8)));
typedef float  f32x4  __attribute__((ext_vector_type(4)));
typedef ushort u16x4  __attribute__((ext_vector_type(4)));
typedef unsigned long long ull;

#define SPLIT1(f, Hm, Lm) { __hip_bfloat16 _h = __float2bfloat16(f); (Hm) = *(ushort*)&_h; \
    __hip_bfloat16 _l = __float2bfloat16((f) - __bfloat162float(_h)); (Lm) = *(ushort*)&_l; }

__device__ inline void st_f32_coh(float* p, float v) {
    __hip_atomic_store(p, v, __ATOMIC_RELAXED, __HIP_MEMORY_SCOPE_AGENT);
}
__device__ inline void st_u16_coh(ushort* p, ushort v) {
    __hip_atomic_store(p, v, __ATOMIC_RELAXED, __HIP_MEMORY_SCOPE_AGENT);
}
__device__ inline void st_u32_coh(unsigned* p, unsigned v) {
    __hip_atomic_store(p, v, __ATOMIC_RELAXED, __HIP_MEMORY_SCOPE_AGENT);
}
__device__ inline void st_f32x2_coh(float* p, float a, float b) {
    union { float f[2]; ull u; } pk;
    pk.f[0] = a; pk.f[1] = b;
    __hip_atomic_store((ull*)p, pk.u, __ATOMIC_RELAXED, __HIP_MEMORY_SCOPE_AGENT);
}

// ---------------- mask codes: mcode[t*B+b] = mt | (mn<<1) ----------------
__global__ __launch_bounds__(256) void k_mask(const int* __restrict__ mask,
                                              int* __restrict__ mcode) {
    int g = blockIdx.x * 256 + threadIdx.x;
    int t = g >> 6, b = g & 63;
    int mt = mask[b * T_ + t] != 0;
    int mn = (t + 1 < T_) ? (mask[b * T_ + t + 1] != 0) : 0;
    mcode[g] = mt | (mn << 1);
}

// ---- x to bf16: Xb[t*64+b][k] = bf16(k<512 ? x[b][t][k] : 0) ----
__global__ __launch_bounds__(256) void k_prepx(const float* __restrict__ x,
                                               ushort* __restrict__ Xh) {
    int g  = blockIdx.x * 256 + threadIdx.x;
    int i4 = g * 4;
    int row = i4 >> 10;
    int k   = i4 & 1023;
    int t = row >> 6, b = row & 63;
    float4 v = make_float4(0.f, 0.f, 0.f, 0.f);
    if (k < 512) v = *(const float4*)&x[((size_t)b * T_ + t) * 512 + k];
    u16x4 h;
    __hip_bfloat16 b0 = __float2bfloat16(v.x); h[0] = *(ushort*)&b0;
    __hip_bfloat16 b1 = __float2bfloat16(v.y); h[1] = *(ushort*)&b1;
    __hip_bfloat16 b2 = __float2bfloat16(v.z); h[2] = *(ushort*)&b2;
    __hip_bfloat16 b3 = __float2bfloat16(v.w); h[3] = *(ushort*)&b3;
    *(u16x4*)&Xh[i4] = h;
}

// ---- transpose + split-bf16: Mt_hi[o][k]+Mt_lo[o][k] ≈ M[k][o]  (M is [D_][O_]) ----
__global__ __launch_bounds__(256) void k_prep(const float* __restrict__ M,
                                              ushort* __restrict__ Mt_hi,
                                              ushort* __restrict__ Mt_lo) {
    __shared__ float ls[64][65];
    int k0 = blockIdx.y * 64;
    int o0 = blockIdx.x * 64;
    int tid = threadIdx.x;
    int r = tid >> 2, cq = tid & 3;
#pragma unroll
    for (int j = 0; j < 4; ++j) {
        float4 v = *(const float4*)&M[(size_t)(k0 + r) * O_ + o0 + cq * 16 + j * 4];
        ls[r][cq * 16 + j * 4 + 0] = v.x;
        ls[r][cq * 16 + j * 4 + 1] = v.y;
        ls[r][cq * 16 + j * 4 + 2] = v.z;
        ls[r][cq * 16 + j * 4 + 3] = v.w;
    }
    __syncthreads();
    int ol = tid >> 2, kq = tid & 3;
    ushort th[16], tl[16];
#pragma unroll
    for (int j = 0; j < 16; ++j) {
        float v = ls[kq * 16 + j][ol];
        SPLIT1(v, th[j], tl[j]);
    }
    size_t base = (size_t)(o0 + ol) * D_ + k0 + kq * 16;
    *(int4*)&Mt_hi[base]     = *(int4*)&th[0];
    *(int4*)&Mt_hi[base + 8] = *(int4*)&th[8];
    *(int4*)&Mt_lo[base]     = *(int4*)&tl[0];
    *(int4*)&Mt_lo[base + 8] = *(int4*)&tl[8];
}

// ------ barrier: sc1-store protocol; per-domain flags ------
__device__ inline void gbar(unsigned* __restrict__ fl, int w, unsigned bar) {
    __syncthreads();
    asm volatile("s_waitcnt vmcnt(0)" ::: "memory");
    if (threadIdx.x == 0)
        __hip_atomic_store(&fl[w], bar, __ATOMIC_RELAXED, __HIP_MEMORY_SCOPE_AGENT);
    if (threadIdx.x < NWG) {
        while (__hip_atomic_load(&fl[threadIdx.x], __ATOMIC_RELAXED,
                                 __HIP_MEMORY_SCOPE_AGENT) < bar)
            __builtin_amdgcn_s_sleep(2);
    }
    __syncthreads();
    __builtin_amdgcn_fence(__ATOMIC_ACQUIRE, "agent");
}

// ===== 4-layer wavefront pipeline, 4 batch domains, 2 WGs/CU co-residency =====
// 384 WGs x 128 thr: dom = bx/96 (16 rows), w = bx%96 (16 cols).
// 2 waves = K-halves. Hi-weights in LDS (64KB); lo-weights streamed from global.
// Slot: A | bar | B(wv1: reduce+tag) ~tag~ C(wv0: gate) | bar.
__global__ __launch_bounds__(128, 1) void k_pipe(
        const float* __restrict__ x,
        const ushort* __restrict__ Xbh,
        ushort* __restrict__ Xrh,
        ushort* __restrict__ Hbh,
        float* __restrict__ Y1, float* __restrict__ Y2,
        float* __restrict__ pstats, float* __restrict__ finals,
        unsigned* __restrict__ ftag, unsigned* __restrict__ flags,
        const ushort* __restrict__ Uth, const ushort* __restrict__ Utl,
        const ushort* __restrict__ Wth, const ushort* __restrict__ Wtl,
        const float* __restrict__ gam, const float* __restrict__ bet,
        const float* __restrict__ bias,
        const int* __restrict__ mcode, float* __restrict__ out) {
    __shared__ __hip_bfloat16 lds[2 * 16 * 1024];   // [U_hi|W_hi] 32KB each
    __shared__ f32x4 ldsc[4][64][2];                // per-layer K-half partials (8KB)
    const int bx = blockIdx.x;
    const int dom = bx / NWG;
    const int w   = bx % NWG;
    const int tid = threadIdx.x;
    const int lane = tid & 63;
    const int kh = tid >> 6;           // wave = K half
    const int lr = lane & 15;
    const int lg = lane >> 4;
    const int c0 = w * 16;
    const int br0 = dom * 16;          // this domain's global row base
    unsigned* fl = flags + dom * 128;
    float* pst   = pstats + (size_t)dom * 64 * NWG * 4;
    float* fin   = finals + (size_t)dom * 64 * 4;
    unsigned* ft = ftag + (size_t)dom * 64;

    // stage hi U/W tiles (cols c0..c0+16) into LDS, XOR-swizzled (128 threads)
    {
        int cl = tid >> 3, kc = tid & 7;
        const ushort* s0 = Uth + (size_t)(c0 + cl) * D_ + kc * 128;
        const ushort* s1 = Wth + (size_t)(c0 + cl) * D_ + kc * 128;
        char* base = (char*)lds;
#pragma unroll
        for (int j = 0; j < 16; ++j) {
            int k = kc * 128 + j * 8;
            int off = (cl * 2048 + k * 2) ^ ((cl & 7) << 4);
            *(int4*)(base + off)         = *(const int4*)(s0 + j * 8);
            *(int4*)(base + 32768 + off) = *(const int4*)(s1 + j * 8);
        }
    }
    __syncthreads();

    const int d = c0 + lr;
    const bool gate_w = (w < 64);
    const bool tanh_w = (w >= 32 && w < 64);
    float g0d = 0.f, g1d = 0.f, cd = 0.f, g0e = 0.f, g1e = 0.f, ce = 0.f;
    if (gate_w) {
        g0d = gam[d]; g1d = gam[O_ + d];
        cd  = bet[d] + bet[O_ + d] + bias[d];
    }
    if (tanh_w) {
        int e = d + 512;
        g0e = gam[e]; g1e = gam[O_ + e];
        ce  = bet[e] + bet[O_ + e] + bias[e];
    }

    // gate-wave (kh==0) register state: rows br0 + lg*4 + j, col d
    float h1r[4][4] = {}, fk1r[4][4] = {};
    float oh_d1[4][4] = {}, oh_d2[4][4] = {}, fkp_d1[4][4] = {};
    f32x4 acc1[4], acc2[4];

    // lo-weight global base pointers (B-fragment: col = lr, k = kh*512 + kloc)
    const ushort* ulo = Utl + (size_t)(c0 + lr) * D_ + kh * 512;
    const ushort* wlo = Wtl + (size_t)(c0 + lr) * D_ + kh * 512;

    unsigned bar = 0;
    for (int s = 0; s < NSLOT; ++s) {
        // ------- phase A: pair-grouped matvecs; hi from LDS, lo from global -------
        bool actv[4];
        const ushort* xs[4];
        const ushort* hs[4];
#pragma unroll
        for (int l = 0; l < 4; ++l) {
            int t = s - 2 * l;
            actv[l] = (t >= 0) && (t < T_);
            int tc = t < 0 ? 0 : (t >= T_ ? T_ - 1 : t);
            if (l == 0)
                xs[l] = Xbh + ((size_t)tc * B_ + br0 + lr) * D_ + kh * 512;
            else
                xs[l] = Xrh + (((size_t)l * 3 + (tc % 3)) * B_ + br0 + lr) * D_ + kh * 512;
            hs[l] = Hbh + ((size_t)l * B_ + br0 + lr) * D_ + kh * 512;
        }
        {
            const char* lb = (const char*)lds;
#pragma unroll
            for (int pg = 0; pg < 2; ++pg) {
                f32x4 c1h[2] = {}, c1l[2] = {}, c2h[2] = {}, c2l[2] = {};
#pragma unroll 4
                for (int kc = 0; kc < 16; ++kc) {
                    int kloc = kc * 32 + lg * 8;
                    int kglob = kh * 512 + kloc;
                    int off = (lr * 2048 + kglob * 2) ^ ((lr & 7) << 4);
                    bf16x8 ubh = *(const bf16x8*)(lb + off);
                    bf16x8 wbh = *(const bf16x8*)(lb + 32768 + off);
                    bf16x8 ubl = *(const bf16x8*)(ulo + kloc);
                    bf16x8 wbl = *(const bf16x8*)(wlo + kloc);
#pragma unroll
                    for (int u = 0; u < 2; ++u) {
                        const int l = pg * 2 + u;
                        bf16x8 xa = *(const bf16x8*)(xs[l] + kloc);
                        bf16x8 ha = *(const bf16x8*)(hs[l] + kloc);
                        c1h[u] = __builtin_amdgcn_mfma_f32_16x16x32_bf16(xa, wbh, c1h[u], 0, 0, 0);
                        c1l[u] = __builtin_amdgcn_mfma_f32_16x16x32_bf16(xa, wbl, c1l[u], 0, 0, 0);
                        c2h[u] = __builtin_amdgcn_mfma_f32_16x16x32_bf16(ha, ubh, c2h[u], 0, 0, 0);
                        c2l[u] = __builtin_amdgcn_mfma_f32_16x16x32_bf16(ha, ubl, c2l[u], 0, 0, 0);
                    }
                }
#pragma unroll
                for (int u = 0; u < 2; ++u) {
                    const int l = pg * 2 + u;
                    acc1[l] = c1h[u] + c1l[u];     // this wave's K-half partial
                    acc2[l] = c2h[u] + c2l[u];
                }
            }
        }
#pragma unroll
        for (int l = 0; l < 4; ++l) {
            if (actv[l] && kh == 1) {
                ldsc[l][lane][0] = acc1[l];
                ldsc[l][lane][1] = acc2[l];
            }
        }
        __syncthreads();
        if (kh == 0) {
#pragma unroll
            for (int l = 0; l < 4; ++l) {
                if (!actv[l]) continue;
                acc1[l] = acc1[l] + ldsc[l][lane][0];
                acc2[l] = acc2[l] + ldsc[l][lane][1];
                // per-row partial stats -> pstats[(l,lrow,w)]
#pragma unroll
                for (int j = 0; j < 4; ++j) {
                    float s1 = acc1[l][j], q1 = s1 * s1;
                    float s2 = acc2[l][j], q2 = s2 * s2;
#pragma unroll
                    for (int m = 1; m < 16; m <<= 1) {
                        s1 += __shfl_xor(s1, m); q1 += __shfl_xor(q1, m);
                        s2 += __shfl_xor(s2, m); q2 += __shfl_xor(q2, m);
                    }
                    if (lr == 0) {
                        int lrow = lg * 4 + j;
                        float* sp = &pst[(((size_t)l * 16 + lrow) * NWG + w) * 4];
                        st_f32x2_coh(sp, s1, q1);
                        st_f32x2_coh(sp + 2, s2, q2);
                    }
                }
                // export tanh-partner cols (w>=64)
                if (w >= 64) {
                    int cexp = c0 + lr - 1024;
#pragma unroll
                    for (int j = 0; j < 4; ++j) {
                        int b = br0 + lg * 4 + j;
                        st_f32_coh(&Y1[((size_t)l * B_ + b) * 512 + cexp], acc1[l][j]);
                        st_f32_coh(&Y2[((size_t)l * B_ + b) * 512 + cexp], acc2[l][j]);
                    }
                }
            }
        }
        gbar(fl, w, ++bar);

        // ------- phase B: stats reduce (wv==1, pair = w < 64) + tag -------
        if (kh == 1 && w < 64) {
            int pair = w;
            const float* pp = &pst[(size_t)pair * NWG * 4];
            float s1 = 0.f, q1 = 0.f, s2 = 0.f, q2 = 0.f;
            if (lane < 32) {
#pragma unroll
                for (int i = 0; i < 3; ++i) {
                    float4 v = *(const float4*)(pp + (lane + i * 32) * 4);
                    s1 += v.x; q1 += v.y; s2 += v.z; q2 += v.w;
                }
            }
#pragma unroll
            for (int m = 1; m < 32; m <<= 1) {
                s1 += __shfl_xor(s1, m); q1 += __shfl_xor(q1, m);
                s2 += __shfl_xor(s2, m); q2 += __shfl_xor(q2, m);
            }
            if (lane == 0) {
                float m1 = s1 * (1.f / O_);
                float v1 = q1 * (1.f / O_) - m1 * m1;
                float i1 = 1.f / (sqrtf(v1 + EPSf) + EPSf);
                float m2 = s2 * (1.f / O_);
                float v2 = q2 * (1.f / O_) - m2 * m2;
                float i2 = 1.f / (sqrtf(v2 + EPSf) + EPSf);
                st_f32x2_coh(&fin[(size_t)pair * 4], m1, i1);
                st_f32x2_coh(&fin[(size_t)pair * 4 + 2], m2, i2);
                asm volatile("s_waitcnt vmcnt(0)" ::: "memory");
                st_u32_coh(&ft[pair], (unsigned)(s + 1));
            }
        }

        // ------- phase C: gating (wv==0, gate WGs); spin-all then burst loads -------
        if (kh == 0 && gate_w) {
            const int lrow0 = lg * 4;
            // 1. spin until all 16 (l,row) tags ready
            for (;;) {
                bool ready = true;
#pragma unroll
                for (int l = 0; l < 4; ++l) {
                    int t = s - 2 * l;
                    if (t < 0 || t >= T_) continue;
                    unsigned t0 = __hip_atomic_load(&ft[l * 16 + lrow0 + 0], __ATOMIC_RELAXED, __HIP_MEMORY_SCOPE_AGENT);
                    unsigned t1 = __hip_atomic_load(&ft[l * 16 + lrow0 + 1], __ATOMIC_RELAXED, __HIP_MEMORY_SCOPE_AGENT);
                    unsigned t2 = __hip_atomic_load(&ft[l * 16 + lrow0 + 2], __ATOMIC_RELAXED, __HIP_MEMORY_SCOPE_AGENT);
                    unsigned t3 = __hip_atomic_load(&ft[l * 16 + lrow0 + 3], __ATOMIC_RELAXED, __HIP_MEMORY_SCOPE_AGENT);
                    unsigned mn4 = min(min(t0, t1), min(t2, t3));
                    ready = ready && (mn4 >= (unsigned)(s + 1));
                }
                if (ready) break;
                __builtin_amdgcn_s_sleep(1);
            }
            // 2. per-layer gating (descending layers)
#pragma unroll
            for (int li = 0; li < 4; ++li) {
                const int l = 3 - li;
                const int lp = (l > 0) ? l - 1 : 0;
                int t = s - 2 * l;
                bool act = (t >= 0) && (t < T_);
                float ohn[4], ofkn[4];
                if (act) {
                    int b_base = br0 + lg * 4;
                    int4 mc4 = *(const int4*)&mcode[t * B_ + b_base];
                    int mcarr[4] = {mc4.x, mc4.y, mc4.z, mc4.w};
                    float4 sv[4];
                    float y1e[4], y2e[4];
#pragma unroll
                    for (int j = 0; j < 4; ++j)
                        sv[j] = *(const float4*)&fin[(size_t)(l * 16 + lrow0 + j) * 4];
                    if (tanh_w) {
#pragma unroll
                        for (int j = 0; j < 4; ++j) {
                            int b = b_base + j;
                            y1e[j] = Y1[((size_t)l * B_ + b) * 512 + (d - 512)];
                            y2e[j] = Y2[((size_t)l * B_ + b) * 512 + (d - 512)];
                        }
                    }
#pragma unroll
                    for (int j = 0; j < 4; ++j) {
                        int b = b_base + j;
                        float m1 = sv[j].x, i1 = sv[j].y, m2 = sv[j].z, i2 = sv[j].w;
                        float y1 = acc1[l][j], y2 = acc2[l][j];
                        float td = g0d * (y1 - m1) * i1 + g1d * (y2 - m2) * i2 + cd;
                        float fkc = fminf(fmaxf(0.2f * td + 0.5f, 0.f), 1.f);
                        float hpad = 0.f;
                        if (tanh_w) {
                            float te = g0e * (y1e[j] - m1) * i1 + g1e * (y2e[j] - m2) * i2 + ce;
                            hpad = tanhf(te);
                        }
                        float xt;
                        if (l == 0)
                            xt = (d < 512) ? x[((size_t)b * T_ + t) * 512 + d] : 0.f;
                        else
                            xt = oh_d2[lp][j];
                        float fkp = (l > 0 && t + 1 < T_) ? fkp_d1[lp][j] : 0.f;
                        float hc = (1.f - fkc) * xt + fkc * hpad;
                        float h  = fkp * h1r[l][j] + (1.f - fkp) * hc;
                        float fk = fkp + (1.f - fkp) * fkc;
                        int mt = mcarr[j] & 1, mn = (mcarr[j] >> 1) & 1;
                        if (mt && !mn) fk = 0.f;
                        float oh  = mt ? h  : h1r[l][j];
                        float ofk = mt ? fk : fk1r[l][j];
                        h1r[l][j] = oh; fk1r[l][j] = ofk;
                        __hip_bfloat16 hb = __float2bfloat16(oh);
                        ushort hi = *(ushort*)&hb;
                        st_u16_coh(Hbh + ((size_t)l * B_ + b) * D_ + d, hi);
                        if (l < 3) {
                            size_t xb = (((size_t)(l + 1) * 3 + (t % 3)) * B_ + b) * D_ + d;
                            st_u16_coh(Xrh + xb, hi);
                        }
                        if (l == 3 && t == T_ - 1 && d >= 512)
                            out[(size_t)b * 512 + (d - 512)] = oh;
                        ohn[j] = oh; ofkn[j] = ofk;
                    }
                }
#pragma unroll
                for (int j = 0; j < 4; ++j) {
                    oh_d2[l][j] = oh_d1[l][j];
                    if (act) { oh_d1[l][j] = ohn[j]; fkp_d1[l][j] = ofkn[j]; }
                }
            }
        }
        gbar(fl, w, ++bar);
    }
}

extern "C" void kernel_launch(void* const* d_in, const int* in_sizes, int n_in,
                              void* d_out, int out_size, void* d_ws, size_t ws_size,
                              hipStream_t stream) {
    (void)in_sizes; (void)n_in; (void)out_size;
    const float* x      = (const float*)d_in[0];
    const int*   mask   = (const int*)d_in[1];
    const float* W      = (const float*)d_in[2];
    const float* U      = (const float*)d_in[3];
    const float* bias   = (const float*)d_in[4];
    const float* gammas = (const float*)d_in[5];
    const float* betas  = (const float*)d_in[6];

    float* ws = (float*)d_ws;
    float* Y1    = ws;                                     // 4*B_*512
    float* Y2    = Y1 + (size_t)4 * B_ * 512;              // 4*B_*512
    float* pstats = Y2 + (size_t)4 * B_ * 512;             // NDOM*64*96*4
    float* finals = pstats + (size_t)NDOM * 64 * NWG * 4;  // NDOM*64*4
    unsigned* ftag  = (unsigned*)(finals + NDOM * 64 * 4); // NDOM*64
    unsigned* flags = ftag + NDOM * 64;                    // NDOM*128
    int* mcode = (int*)(flags + NDOM * 128);               // TB_
    ushort* Xbh = (ushort*)(mcode + TB_);                  // TB_*D_
    ushort* Xrh = Xbh + (size_t)TB_ * D_;                  // 4*3*B_*D_
    ushort* Hbh = Xrh + (size_t)4 * 3 * B_ * D_;           // 4*B_*D_
    ushort* Uth = Hbh + (size_t)4 * B_ * D_;               // O_*D_
    ushort* Utl = Uth + (size_t)O_ * D_;
    ushort* Wth = Utl + (size_t)O_ * D_;
    ushort* Wtl = Wth + (size_t)O_ * D_;
    size_t need_bytes = ((char*)(Wtl + (size_t)O_ * D_)) - ((char*)d_ws);
    if (ws_size < need_bytes) return;

    k_prepx<<<TB_ * D_ / 4 / 256, 256, 0, stream>>>(x, Xbh);
    k_mask<<<TB_ / 256, 256, 0, stream>>>(mask, mcode);
    k_prep<<<dim3(O_ / 64, D_ / 64), 256, 0, stream>>>(U, Uth, Utl);
    k_prep<<<dim3(O_ / 64, D_ / 64), 256, 0, stream>>>(W, Wth, Wtl);
    (void)hipMemsetAsync(Hbh, 0, sizeof(ushort) * (size_t)4 * B_ * D_, stream);
    (void)hipMemsetAsync(pstats, 0, sizeof(float) * (size_t)NDOM * 64 * NWG * 4, stream);
    (void)hipMemsetAsync(ftag, 0, sizeof(unsigned) * NDOM * 64, stream);
    (void)hipMemsetAsync(flags, 0, sizeof(unsigned) * NDOM * 128, stream);

    k_pipe<<<NDOM * NWG, 128, 0, stream>>>(x, Xbh, Xrh, Hbh,
                                           Y1, Y2, pstats, finals, ftag, flags,
                                           Uth, Utl, Wth, Wtl,
                                           gammas, betas, bias, mcode, (float*)d_out);
}

// Round 21
// 12737.347 us; speedup vs baseline: 1.1922x; 1.1922x over previous
//
#include <hip/hip_runtime.h>
#include <hip/hip_bf16.h>
#include <math.h>

#define B_   64
#define T_   256
#define DIN_ 512
#define H_   512
#define D_   1024
#define O_   1536
#define TB_  (T_*B_)
#define EPSf 1e-5f
#define NWG  96          // col-WGs per domain; WG w owns y-cols [16w,16w+16)
#define NSLOT (T_ + 6)   // wavefront slots: t = s - 2l

typedef short  bf16x8 __attribute__((ext_vector_type(8)));
typedef float  f32x4  __attribute__((ext_vector_type(4)));
typedef ushort u16x4  __attribute__((ext_vector_type(4)));
typedef unsigned long long ull;

#define SPLIT1(f, Hm, Lm) { __hip_bfloat16 _h = __float2bfloat16(f); (Hm) = *(ushort*)&_h; \
    __hip_bfloat16 _l = __float2bfloat16((f) - __bfloat162float(_h)); (Lm) = *(ushort*)&_l; }

__device__ inline void st_f32_coh(float* p, float v) {
    __hip_atomic_store(p, v, __ATOMIC_RELAXED, __HIP_MEMORY_SCOPE_AGENT);
}
__device__ inline void st_u16_coh(ushort* p, ushort v) {
    __hip_atomic_store(p, v, __ATOMIC_RELAXED, __HIP_MEMORY_SCOPE_AGENT);
}
__device__ inline void st_u32_coh(unsigned* p, unsigned v) {
    __hip_atomic_store(p, v, __ATOMIC_RELAXED, __HIP_MEMORY_SCOPE_AGENT);
}
__device__ inline void st_f32x2_coh(float* p, float a, float b) {
    union { float f[2]; ull u; } pk;
    pk.f[0] = a; pk.f[1] = b;
    __hip_atomic_store((ull*)p, pk.u, __ATOMIC_RELAXED, __HIP_MEMORY_SCOPE_AGENT);
}

// ---------------- mask codes: mcode[t*B+b] = mt | (mn<<1) ----------------
__global__ __launch_bounds__(256) void k_mask(const int* __restrict__ mask,
                                              int* __restrict__ mcode) {
    int g = blockIdx.x * 256 + threadIdx.x;
    int t = g >> 6, b = g & 63;
    int mt = mask[b * T_ + t] != 0;
    int mn = (t + 1 < T_) ? (mask[b * T_ + t + 1] != 0) : 0;
    mcode[g] = mt | (mn << 1);
}

// ---- x to bf16: Xb[t*64+b][k] = bf16(k<512 ? x[b][t][k] : 0) ----
__global__ __launch_bounds__(256) void k_prepx(const float* __restrict__ x,
                                               ushort* __restrict__ Xh) {
    int g  = blockIdx.x * 256 + threadIdx.x;
    int i4 = g * 4;
    int row = i4 >> 10;
    int k   = i4 & 1023;
    int t = row >> 6, b = row & 63;
    float4 v = make_float4(0.f, 0.f, 0.f, 0.f);
    if (k < 512) v = *(const float4*)&x[((size_t)b * T_ + t) * 512 + k];
    u16x4 h;
    __hip_bfloat16 b0 = __float2bfloat16(v.x); h[0] = *(ushort*)&b0;
    __hip_bfloat16 b1 = __float2bfloat16(v.y); h[1] = *(ushort*)&b1;
    __hip_bfloat16 b2 = __float2bfloat16(v.z); h[2] = *(ushort*)&b2;
    __hip_bfloat16 b3 = __float2bfloat16(v.w); h[3] = *(ushort*)&b3;
    *(u16x4*)&Xh[i4] = h;
}

// ---- transpose + split-bf16: Mt_hi[o][k]+Mt_lo[o][k] ≈ M[k][o]  (M is [D_][O_]) ----
__global__ __launch_bounds__(256) void k_prep(const float* __restrict__ M,
                                              ushort* __restrict__ Mt_hi,
                                              ushort* __restrict__ Mt_lo) {
    __shared__ float ls[64][65];
    int k0 = blockIdx.y * 64;
    int o0 = blockIdx.x * 64;
    int tid = threadIdx.x;
    int r = tid >> 2, cq = tid & 3;
#pragma unroll
    for (int j = 0; j < 4; ++j) {
        float4 v = *(const float4*)&M[(size_t)(k0 + r) * O_ + o0 + cq * 16 + j * 4];
        ls[r][cq * 16 + j * 4 + 0] = v.x;
        ls[r][cq * 16 + j * 4 + 1] = v.y;
        ls[r][cq * 16 + j * 4 + 2] = v.z;
        ls[r][cq * 16 + j * 4 + 3] = v.w;
    }
    __syncthreads();
    int ol = tid >> 2, kq = tid & 3;
    ushort th[16], tl[16];
#pragma unroll
    for (int j = 0; j < 16; ++j) {
        float v = ls[kq * 16 + j][ol];
        SPLIT1(v, th[j], tl[j]);
    }
    size_t base = (size_t)(o0 + ol) * D_ + k0 + kq * 16;
    *(int4*)&Mt_hi[base]     = *(int4*)&th[0];
    *(int4*)&Mt_hi[base + 8] = *(int4*)&th[8];
    *(int4*)&Mt_lo[base]     = *(int4*)&tl[0];
    *(int4*)&Mt_lo[base + 8] = *(int4*)&tl[8];
}

// ------ barrier: sc1-store protocol (verified round 8); per-domain flags ------
__device__ inline void gbar(unsigned* __restrict__ fl, int w, unsigned bar) {
    __syncthreads();
    asm volatile("s_waitcnt vmcnt(0)" ::: "memory");
    if (threadIdx.x == 0)
        __hip_atomic_store(&fl[w], bar, __ATOMIC_RELAXED, __HIP_MEMORY_SCOPE_AGENT);
    if (threadIdx.x < NWG) {
        while (__hip_atomic_load(&fl[threadIdx.x], __ATOMIC_RELAXED,
                                 __HIP_MEMORY_SCOPE_AGENT) < bar)
            __builtin_amdgcn_s_sleep(2);
    }
    __syncthreads();
    __builtin_amdgcn_fence(__ATOMIC_ACQUIRE, "agent");
}

// ============ 4-layer wavefront pipeline, 2 batch domains (XCD-parity) ============
// 192 WGs: dom = bx&1 (parity -> disjoint XCD sets), w = bx>>1 owns cols [16w,+16).
// waves: rt = wv&1 (16-row tile), kh = wv>>1 (K-half); deferred LDS combine.
// slot: A(all layers, 1 sync) | bar | B(reduce+tag) ~~tag-all~~ C(gate) | bar.
__global__ __launch_bounds__(256, 1) void k_pipe(
        const float* __restrict__ x,
        const ushort* __restrict__ Xbh,
        ushort* __restrict__ Xrh,
        ushort* __restrict__ Hbh,
        float* __restrict__ Y1, float* __restrict__ Y2,
        float* __restrict__ pstats, float* __restrict__ finals,
        unsigned* __restrict__ ftag, unsigned* __restrict__ flags,
        const ushort* __restrict__ Uth, const ushort* __restrict__ Utl,
        const ushort* __restrict__ Wth, const ushort* __restrict__ Wtl,
        const float* __restrict__ gam, const float* __restrict__ bet,
        const float* __restrict__ bias,
        const int* __restrict__ mcode, float* __restrict__ out) {
    __shared__ __hip_bfloat16 lds[4 * 16 * 1024];   // [U_hi|U_lo|W_hi|W_lo] 32KB each
    __shared__ f32x4 ldsc[4][2][64][2];             // per-layer K-half partials (16KB)
    const int bx = blockIdx.x;
    const int dom = bx & 1;            // parity -> even/odd XCDs (L2 locality)
    const int w   = bx >> 1;
    const int tid = threadIdx.x;
    const int lane = tid & 63;
    const int wv = tid >> 6;
    const int rt = wv & 1;             // row tile within domain
    const int kh = wv >> 1;            // K half
    const int lr = lane & 15;
    const int lg = lane >> 4;
    const int c0 = w * 16;
    const int br0 = dom * 32 + rt * 16;     // global row base of this wave's tile
    unsigned* fl = flags + dom * 128;
    float* pst   = pstats + (size_t)dom * 4 * 32 * NWG * 4;
    float* fin   = finals + (size_t)dom * 128 * 4;
    unsigned* ft = ftag + (size_t)dom * 128;

    // stage U/W tiles (cols c0..c0+16) into LDS, XOR-swizzled
    {
        int cl = tid >> 4, kc = tid & 15;
        const ushort* srcs0 = Uth + (size_t)(c0 + cl) * D_ + kc * 64;
        const ushort* srcs1 = Utl + (size_t)(c0 + cl) * D_ + kc * 64;
        const ushort* srcs2 = Wth + (size_t)(c0 + cl) * D_ + kc * 64;
        const ushort* srcs3 = Wtl + (size_t)(c0 + cl) * D_ + kc * 64;
        char* base = (char*)lds;
#pragma unroll
        for (int j = 0; j < 8; ++j) {
            int k = kc * 64 + j * 8;
            int off = (cl * 2048 + k * 2) ^ ((cl & 7) << 4);
            *(int4*)(base + off)           = *(const int4*)(srcs0 + j * 8);
            *(int4*)(base + 32768 + off)   = *(const int4*)(srcs1 + j * 8);
            *(int4*)(base + 65536 + off)   = *(const int4*)(srcs2 + j * 8);
            *(int4*)(base + 98304 + off)   = *(const int4*)(srcs3 + j * 8);
        }
    }
    __syncthreads();

    const int d = c0 + lr;
    const bool gate_w = (w < 64);
    const bool tanh_w = (w >= 32 && w < 64);
    float g0d = 0.f, g1d = 0.f, cd = 0.f, g0e = 0.f, g1e = 0.f, ce = 0.f;
    if (gate_w) {
        g0d = gam[d]; g1d = gam[O_ + d];
        cd  = bet[d] + bet[O_ + d] + bias[d];
    }
    if (tanh_w) {
        int e = d + 512;
        g0e = gam[e]; g1e = gam[O_ + e];
        ce  = bet[e] + bet[O_ + e] + bias[e];
    }

    // gate-wave register state (waves wv<2; wave wv owns rows dom*32+wv*16..+16)
    float h1r[4][4] = {}, fk1r[4][4] = {};
    float oh_d1[4][4] = {}, oh_d2[4][4] = {}, fkp_d1[4][4] = {};
    f32x4 acc1[4], acc2[4];

    unsigned bar = 0;
    for (int s = 0; s < NSLOT; ++s) {
        // ------- phase A: all-layer matvecs (K-split, deferred combine) -------
        f32x4 p1[4], p2[4];
#pragma unroll
        for (int l = 0; l < 4; ++l) {
            int t = s - 2 * l;
            bool act = (t >= 0) && (t < T_);
            p1[l] = (f32x4){0,0,0,0};
            p2[l] = (f32x4){0,0,0,0};
            if (act) {
                const ushort* xsh;
                if (l == 0) {
                    xsh = Xbh + ((size_t)t * B_ + br0 + lr) * D_ + kh * 512;
                } else {
                    xsh = Xrh + (((size_t)l * 3 + (t % 3)) * B_ + br0 + lr) * D_ + kh * 512;
                }
                const ushort* hsh = Hbh + ((size_t)l * B_ + br0 + lr) * D_ + kh * 512;
                const char* lb = (const char*)lds;
                f32x4 a10 = {0,0,0,0}, a11 = {0,0,0,0};
                f32x4 a20 = {0,0,0,0}, a21 = {0,0,0,0};
#pragma unroll 4
                for (int kc = 0; kc < 16; ++kc) {
                    int kloc = kc * 32 + lg * 8;
                    int kglob = kh * 512 + kloc;
                    int off = (lr * 2048 + kglob * 2) ^ ((lr & 7) << 4);
                    bf16x8 xa = *(const bf16x8*)(xsh + kloc);
                    bf16x8 ha = *(const bf16x8*)(hsh + kloc);
                    bf16x8 ubh = *(const bf16x8*)(lb + off);
                    bf16x8 ubl = *(const bf16x8*)(lb + 32768 + off);
                    bf16x8 wbh = *(const bf16x8*)(lb + 65536 + off);
                    bf16x8 wbl = *(const bf16x8*)(lb + 98304 + off);
                    a10 = __builtin_amdgcn_mfma_f32_16x16x32_bf16(xa, wbh, a10, 0, 0, 0);
                    a11 = __builtin_amdgcn_mfma_f32_16x16x32_bf16(xa, wbl, a11, 0, 0, 0);
                    a20 = __builtin_amdgcn_mfma_f32_16x16x32_bf16(ha, ubh, a20, 0, 0, 0);
                    a21 = __builtin_amdgcn_mfma_f32_16x16x32_bf16(ha, ubl, a21, 0, 0, 0);
                }
                p1[l] = a10 + a11;
                p2[l] = a20 + a21;
                if (kh == 1) {
                    ldsc[l][rt][lane][0] = p1[l];
                    ldsc[l][rt][lane][1] = p2[l];
                }
            }
        }
        __syncthreads();
        if (kh == 0) {
#pragma unroll
            for (int l = 0; l < 4; ++l) {
                int t = s - 2 * l;
                bool act = (t >= 0) && (t < T_);
                if (!act) continue;
                acc1[l] = p1[l] + ldsc[l][rt][lane][0];
                acc2[l] = p2[l] + ldsc[l][rt][lane][1];
                // per-row partial stats -> pstats[(l,lrow,w)] (no contention)
#pragma unroll
                for (int j = 0; j < 4; ++j) {
                    float s1 = acc1[l][j], q1 = s1 * s1;
                    float s2 = acc2[l][j], q2 = s2 * s2;
#pragma unroll
                    for (int m = 1; m < 16; m <<= 1) {
                        s1 += __shfl_xor(s1, m); q1 += __shfl_xor(q1, m);
                        s2 += __shfl_xor(s2, m); q2 += __shfl_xor(q2, m);
                    }
                    if (lr == 0) {
                        int lrow = rt * 16 + lg * 4 + j;
                        float* sp = &pst[(((size_t)l * 32 + lrow) * NWG + w) * 4];
                        st_f32x2_coh(sp, s1, q1);
                        st_f32x2_coh(sp + 2, s2, q2);
                    }
                }
                // export tanh-partner cols (w>=64)
                if (w >= 64) {
                    int cexp = c0 + lr - 1024;
#pragma unroll
                    for (int j = 0; j < 4; ++j) {
                        int b = br0 + lg * 4 + j;
                        st_f32_coh(&Y1[((size_t)l * B_ + b) * 512 + cexp], acc1[l][j]);
                        st_f32_coh(&Y2[((size_t)l * B_ + b) * 512 + cexp], acc2[l][j]);
                    }
                }
            }
        }
        gbar(fl, w, ++bar);

        // ------- phase B: stats reduce (pair = w + 96*wv, wv<2) + tag -------
        if (wv < 2) {
            int pair = w + NWG * wv;
            if (pair < 128) {
                const float* pp = &pst[(size_t)pair * NWG * 4];
                float s1 = 0.f, q1 = 0.f, s2 = 0.f, q2 = 0.f;
                if (lane < 32) {
#pragma unroll
                    for (int i = 0; i < 3; ++i) {
                        float4 v = *(const float4*)(pp + (lane + i * 32) * 4);
                        s1 += v.x; q1 += v.y; s2 += v.z; q2 += v.w;
                    }
                }
#pragma unroll
                for (int m = 1; m < 32; m <<= 1) {
                    s1 += __shfl_xor(s1, m); q1 += __shfl_xor(q1, m);
                    s2 += __shfl_xor(s2, m); q2 += __shfl_xor(q2, m);
                }
                if (lane == 0) {
                    float m1 = s1 * (1.f / O_);
                    float v1 = q1 * (1.f / O_) - m1 * m1;
                    float i1 = 1.f / (sqrtf(v1 + EPSf) + EPSf);
                    float m2 = s2 * (1.f / O_);
                    float v2 = q2 * (1.f / O_) - m2 * m2;
                    float i2 = 1.f / (sqrtf(v2 + EPSf) + EPSf);
                    st_f32x2_coh(&fin[(size_t)pair * 4], m1, i1);
                    st_f32x2_coh(&fin[(size_t)pair * 4 + 2], m2, i2);
                    asm volatile("s_waitcnt vmcnt(0)" ::: "memory");
                    st_u32_coh(&ft[pair], (unsigned)(s + 1));
                }
            }
        }

        // ------- phase C: gating (waves wv<2); spin-all then burst loads -------
        if (gate_w && wv < 2) {
            const int lrow0 = wv * 16 + lg * 4;       // this thread's first local row
            // 1. spin until ALL 16 (l,row) tags ready — parallel polls per pass
            for (;;) {
                bool ready = true;
#pragma unroll
                for (int l = 0; l < 4; ++l) {
                    int t = s - 2 * l;
                    if (t < 0 || t >= T_) continue;
                    unsigned t0 = __hip_atomic_load(&ft[l * 32 + lrow0 + 0], __ATOMIC_RELAXED, __HIP_MEMORY_SCOPE_AGENT);
                    unsigned t1 = __hip_atomic_load(&ft[l * 32 + lrow0 + 1], __ATOMIC_RELAXED, __HIP_MEMORY_SCOPE_AGENT);
                    unsigned t2 = __hip_atomic_load(&ft[l * 32 + lrow0 + 2], __ATOMIC_RELAXED, __HIP_MEMORY_SCOPE_AGENT);
                    unsigned t3 = __hip_atomic_load(&ft[l * 32 + lrow0 + 3], __ATOMIC_RELAXED, __HIP_MEMORY_SCOPE_AGENT);
                    unsigned mn4 = min(min(t0, t1), min(t2, t3));
                    ready = ready && (mn4 >= (unsigned)(s + 1));
                }
                if (ready) break;
                __builtin_amdgcn_s_sleep(1);
            }
            // 2. per-layer: burst-load finals (plain: L2 fresh-for-slot) + mc + y, compute
#pragma unroll
            for (int li = 0; li < 4; ++li) {
                const int l = 3 - li;
                const int lp = (l > 0) ? l - 1 : 0;
                int t = s - 2 * l;
                bool act = (t >= 0) && (t < T_);
                float ohn[4], ofkn[4];
                if (act) {
                    int b_base = dom * 32 + wv * 16 + lg * 4;
                    int4 mc4 = *(const int4*)&mcode[t * B_ + b_base];
                    int mcarr[4] = {mc4.x, mc4.y, mc4.z, mc4.w};
                    float4 sv[4];
                    float y1e[4], y2e[4];
#pragma unroll
                    for (int j = 0; j < 4; ++j)
                        sv[j] = *(const float4*)&fin[(size_t)(l * 32 + lrow0 + j) * 4];
                    if (tanh_w) {
#pragma unroll
                        for (int j = 0; j < 4; ++j) {
                            int b = b_base + j;
                            y1e[j] = Y1[((size_t)l * B_ + b) * 512 + (d - 512)];
                            y2e[j] = Y2[((size_t)l * B_ + b) * 512 + (d - 512)];
                        }
                    }
#pragma unroll
                    for (int j = 0; j < 4; ++j) {
                        int b = b_base + j;
                        float m1 = sv[j].x, i1 = sv[j].y, m2 = sv[j].z, i2 = sv[j].w;
                        float y1 = acc1[l][j], y2 = acc2[l][j];
                        float td = g0d * (y1 - m1) * i1 + g1d * (y2 - m2) * i2 + cd;
                        float fkc = fminf(fmaxf(0.2f * td + 0.5f, 0.f), 1.f);
                        float hpad = 0.f;
                        if (tanh_w) {
                            float te = g0e * (y1e[j] - m1) * i1 + g1e * (y2e[j] - m2) * i2 + ce;
                            hpad = tanhf(te);
                        }
                        float xt;
                        if (l == 0)
                            xt = (d < 512) ? x[((size_t)b * T_ + t) * 512 + d] : 0.f;
                        else
                            xt = oh_d2[lp][j];
                        float fkp = (l > 0 && t + 1 < T_) ? fkp_d1[lp][j] : 0.f;
                        float hc = (1.f - fkc) * xt + fkc * hpad;
                        float h  = fkp * h1r[l][j] + (1.f - fkp) * hc;
                        float fk = fkp + (1.f - fkp) * fkc;
                        int mt = mcarr[j] & 1, mn = (mcarr[j] >> 1) & 1;
                        if (mt && !mn) fk = 0.f;
                        float oh  = mt ? h  : h1r[l][j];
                        float ofk = mt ? fk : fk1r[l][j];
                        h1r[l][j] = oh; fk1r[l][j] = ofk;
                        __hip_bfloat16 hb = __float2bfloat16(oh);
                        ushort hi = *(ushort*)&hb;
                        st_u16_coh(Hbh + ((size_t)l * B_ + b) * D_ + d, hi);
                        if (l < 3) {
                            size_t xb = (((size_t)(l + 1) * 3 + (t % 3)) * B_ + b) * D_ + d;
                            st_u16_coh(Xrh + xb, hi);
                        }
                        if (l == 3 && t == T_ - 1 && d >= 512)
                            out[(size_t)b * 512 + (d - 512)] = oh;
                        ohn[j] = oh; ofkn[j] = ofk;
                    }
                }
#pragma unroll
                for (int j = 0; j < 4; ++j) {
                    oh_d2[l][j] = oh_d1[l][j];
                    if (act) { oh_d1[l][j] = ohn[j]; fkp_d1[l][j] = ofkn[j]; }
                }
            }
        }
        gbar(fl, w, ++bar);
    }
}

extern "C" void kernel_launch(void* const* d_in, const int* in_sizes, int n_in,
                              void* d_out, int out_size, void* d_ws, size_t ws_size,
                              hipStream_t stream) {
    (void)in_sizes; (void)n_in; (void)out_size;
    const float* x      = (const float*)d_in[0];
    const int*   mask   = (const int*)d_in[1];
    const float* W      = (const float*)d_in[2];
    const float* U      = (const float*)d_in[3];
    const float* bias   = (const float*)d_in[4];
    const float* gammas = (const float*)d_in[5];
    const float* betas  = (const float*)d_in[6];

    float* ws = (float*)d_ws;
    float* Y1    = ws;                                     // 4*B_*512
    float* Y2    = Y1 + (size_t)4 * B_ * 512;              // 4*B_*512
    float* pstats = Y2 + (size_t)4 * B_ * 512;             // 2*4*32*96*4
    float* finals = pstats + (size_t)2 * 4 * 32 * NWG * 4; // 2*128*4
    unsigned* ftag  = (unsigned*)(finals + 2 * 128 * 4);   // 2*128
    unsigned* flags = ftag + 2 * 128;                      // 256
    int* mcode = (int*)(flags + 256);                      // TB_
    ushort* Xbh = (ushort*)(mcode + TB_);                  // TB_*D_
    ushort* Xrh = Xbh + (size_t)TB_ * D_;                  // 4*3*B_*D_
    ushort* Hbh = Xrh + (size_t)4 * 3 * B_ * D_;           // 4*B_*D_
    ushort* Uth = Hbh + (size_t)4 * B_ * D_;               // O_*D_
    ushort* Utl = Uth + (size_t)O_ * D_;
    ushort* Wth = Utl + (size_t)O_ * D_;
    ushort* Wtl = Wth + (size_t)O_ * D_;
    size_t need_bytes = ((char*)(Wtl + (size_t)O_ * D_)) - ((char*)d_ws);
    if (ws_size < need_bytes) return;

    k_prepx<<<TB_ * D_ / 4 / 256, 256, 0, stream>>>(x, Xbh);
    k_mask<<<TB_ / 256, 256, 0, stream>>>(mask, mcode);
    k_prep<<<dim3(O_ / 64, D_ / 64), 256, 0, stream>>>(U, Uth, Utl);
    k_prep<<<dim3(O_ / 64, D_ / 64), 256, 0, stream>>>(W, Wth, Wtl);
    (void)hipMemsetAsync(Hbh, 0, sizeof(ushort) * (size_t)4 * B_ * D_, stream);
    (void)hipMemsetAsync(pstats, 0, sizeof(float) * (size_t)2 * 4 * 32 * NWG * 4, stream);
    (void)hipMemsetAsync(ftag, 0, sizeof(unsigned) * 2 * 128, stream);
    (void)hipMemsetAsync(flags, 0, sizeof(unsigned) * 256, stream);

    k_pipe<<<2 * NWG, 256, 0, stream>>>(x, Xbh, Xrh, Hbh,
                                        Y1, Y2, pstats, finals, ftag, flags,
                                        Uth, Utl, Wth, Wtl,
                                        gammas, betas, bias, mcode, (float*)d_out);
}